// Round 24
// baseline (260.128 us; speedup 1.0000x reference)
//
#include <hip/hip_runtime.h>

#define HID 10
#define TT  2048
#define BB  4096

typedef float f2 __attribute__((ext_vector_type(2)));

static __device__ __forceinline__ f2 pkmul(f2 a, f2 b) {
    f2 d; asm("v_pk_mul_f32 %0, %1, %2" : "=v"(d) : "v"(a), "v"(b)); return d;
}
static __device__ __forceinline__ f2 pkfma(f2 a, f2 b, f2 c) {
    f2 d; asm("v_pk_fma_f32 %0, %1, %2, %3" : "=v"(d) : "v"(a), "v"(b), "v"(c)); return d;
}

__device__ __forceinline__ float fast_tanh(float x) {
    // tanh(x) = 1 - 2/(exp2(x*2*log2e) + 1); saturates correctly at +-inf
    float e = exp2f(x * 2.885390081777926814f);
    float r = __builtin_amdgcn_rcpf(e + 1.0f);
    return fmaf(-2.0f, r, 1.0f);
}

// single-chain dot (filler phases: issue-minimal)
#define PKDOT(ACC, W, H)                 \
    ACC = pkmul(W[0], H[0]);             \
    ACC = pkfma(W[1], H[1], ACC);        \
    ACC = pkfma(W[2], H[2], ACC);        \
    ACC = pkfma(W[3], H[3], ACC);        \
    ACC = pkfma(W[4], H[4], ACC);

// split-chain dot (chain phases: 3+2 dep chains, ~6-8 cyc shorter)
#define PKDOT2(A0, A1, W, H)             \
    A0 = pkmul(W[0], H[0]);              \
    A1 = pkmul(W[1], H[1]);              \
    A0 = pkfma(W[2], H[2], A0);          \
    A1 = pkfma(W[3], H[3], A1);          \
    A0 = pkfma(W[4], H[4], A0);

// R23 (254us best) + 32-STEP EPOCHS (barriers 129 -> 66; u-ring 64 slots,
// A writes {32m-1..32m+30} mod 64, B reads the complementary 32-window) and
// split-chain recurrence dots (chain-phase only).
//   wave A: h0 recurrence; u(i-1) = Wih1.h0(i-1)+b1 on OLD H0 (readback
//           cover); one f32/lane publish. Lane10 publishes b_out.
//   wave B: h1 recurrence lag-33; lane10 rides Wout -> pre-tanh = out(j-1);
//           lag-carry quad stores. setprio(1) around each chain phase;
//           half-wave bank-phase permute {0,16,8,24}.
__global__ void __launch_bounds__(128) rnn_kernel(
    const float* __restrict__ x,    const float* __restrict__ hs,
    const float* __restrict__ Wih0, const float* __restrict__ Whh0,
    const float* __restrict__ bih0, const float* __restrict__ bhh0,
    const float* __restrict__ Wih1, const float* __restrict__ Whh1,
    const float* __restrict__ bih1, const float* __restrict__ bhh1,
    const float* __restrict__ Wout, const float* __restrict__ boutp,
    float* __restrict__ out)
{
    const int tid  = threadIdx.x;
    const bool isA = tid < 64;
    const int lane = tid & 15;           // hidden unit slot
    const int grp  = (tid >> 4) & 3;     // row within block
    const int row  = blockIdx.x * 4 + grp;
    const bool act = (lane < HID);
    const bool ol  = (lane == HID);      // rider lane

    // stride 1064 floats (mod 32 = 8); permuted bases {0,2,1,3} -> half-wave
    // bank phases {0,16}/{8,24}. Regions per group: u-ring [64][16] f32 @0,
    // h0 buf @1024, h1 buf @1040.
    __shared__ float lds[4 * 1064];
    const int pg = ((grp << 1) | (grp >> 1)) & 3;   // {0,2,1,3}
    float* base = &lds[pg * 1064];
    float* up   = base + lane;           // u-ring lane pointer
    float* h0b  = base + 1024;
    float* h1b  = base + 1040;

    const float* xrow = x   + (size_t)row * TT;
    float*       orow = out + (size_t)row * TT;

    // ---- role state ----
    f2 W0[5], W1[5], W2[5], H0[5], H1[5];
    float wih0i = 0.f, b0c = 0.f, ub = 0.f, obias = 0.f;
    float hown = 0.f;
    float4 xq0, xq1, xq2, xq3, xq4, xq5, xq6, xq7;
    float P1 = 0.f, P2 = 0.f;

    if (isA) {
        #pragma unroll
        for (int j = 0; j < 5; ++j) {
            W0[j] = act ? f2{Whh0[lane*HID + 2*j], Whh0[lane*HID + 2*j+1]}
                        : f2{0.f, 0.f};
            W1[j] = act ? f2{Wih1[lane*HID + 2*j], Wih1[lane*HID + 2*j+1]}
                        : f2{0.f, 0.f};
            H0[j] = f2{hs[row*HID + 2*j], hs[row*HID + 2*j+1]};
        }
        wih0i = act ? Wih0[lane] : 0.f;
        b0c   = act ? (bih0[lane] + bhh0[lane]) : 0.f;
        ub    = act ? (bih1[lane] + bhh1[lane]) : (ol ? boutp[0] : 0.f);
        hown  = act ? hs[row*HID + lane] : 0.f;
        xq0 = *(const float4*)(xrow);      xq1 = *(const float4*)(xrow + 4);
        xq2 = *(const float4*)(xrow + 8);  xq3 = *(const float4*)(xrow + 12);
        xq4 = *(const float4*)(xrow + 16); xq5 = *(const float4*)(xrow + 20);
        xq6 = *(const float4*)(xrow + 24); xq7 = *(const float4*)(xrow + 28);
    } else {
        #pragma unroll
        for (int j = 0; j < 5; ++j) {
            W2[j] = act ? f2{Whh1[lane*HID + 2*j], Whh1[lane*HID + 2*j+1]}
                  : (ol ? f2{Wout[2*j], Wout[2*j+1]} : f2{0.f, 0.f});
            H1[j] = f2{hs[BB*HID + row*HID + 2*j], hs[BB*HID + row*HID + 2*j+1]};
        }
        obias = ol ? boutp[0] : 0.f;
    }

    // A epochs 0..63 (steps i = 32m..32m+31, publishes u(32m-1..32m+30));
    // B epochs 1..64 (j = 32(m-1)-1..32(m-1)+30, lag-33 behind A's window).
    for (int m = 0; m <= 64; ++m) {
        if (isA) {
            if (m <= 63) {
                const int mn = (m + 1 <= 63) ? m + 1 : 63;
                const float4 n0 = *(const float4*)(xrow + 32 * mn);
                const float4 n1 = *(const float4*)(xrow + 32 * mn + 4);
                const float4 n2 = *(const float4*)(xrow + 32 * mn + 8);
                const float4 n3 = *(const float4*)(xrow + 32 * mn + 12);
                const float4 n4 = *(const float4*)(xrow + 32 * mn + 16);
                const float4 n5 = *(const float4*)(xrow + 32 * mn + 20);
                const float4 n6 = *(const float4*)(xrow + 32 * mn + 24);
                const float4 n7 = *(const float4*)(xrow + 32 * mn + 28);
                const float xs[32] = {
                    xq0.x, xq0.y, xq0.z, xq0.w, xq1.x, xq1.y, xq1.z, xq1.w,
                    xq2.x, xq2.y, xq2.z, xq2.w, xq3.x, xq3.y, xq3.z, xq3.w,
                    xq4.x, xq4.y, xq4.z, xq4.w, xq5.x, xq5.y, xq5.z, xq5.w,
                    xq6.x, xq6.y, xq6.z, xq6.w, xq7.x, xq7.y, xq7.z, xq7.w};
                const int sb = (m & 1) * 32;
                #pragma unroll
                for (int k = 0; k < 32; ++k) {
                    // ---- chain phase: prio 1, split-chain dot ----
                    __builtin_amdgcn_s_setprio(1);
                    f2 a0, a1; PKDOT2(a0, a1, W0, H0);
                    const float s0 = fmaf(xs[k], wih0i, b0c);
                    hown = fast_tanh(((s0 + a0.x) + a0.y) + (a1.x + a1.y));
                    h0b[lane] = hown;
                    __builtin_amdgcn_s_setprio(0);
                    __builtin_amdgcn_wave_barrier();
                    // ---- filler phase: readback + u-dot on OLD H0 ----
                    const float4 r0 = *(const float4*)(h0b);
                    const float4 r1 = *(const float4*)(h0b + 4);
                    const f2     r2 = *(const f2*)(h0b + 8);
                    f2 uc; PKDOT(uc, W1, H0);
                    up[((sb + k + 63) & 63) * 16] = (ub + uc.x) + uc.y;
                    H0[0] = f2{r0.x, r0.y}; H0[1] = f2{r0.z, r0.w};
                    H0[2] = f2{r1.x, r1.y}; H0[3] = f2{r1.z, r1.w};
                    H0[4] = r2;
                }
                xq0 = n0; xq1 = n1; xq2 = n2; xq3 = n3;
                xq4 = n4; xq5 = n5; xq6 = n6; xq7 = n7;
            }
        } else {
            if (m >= 1) {
                const int sbB = ((m - 1) & 1) * 32;
                float u[32];
                #pragma unroll
                for (int k = 0; k < 32; ++k)
                    u[k] = up[((sbB + k + 63) & 63) * 16];
                float c[32];
                #pragma unroll
                for (int k = 0; k < 32; ++k) {
                    // j = 32(m-1)-1+k; h1(j) = tanh(u(j) + Whh1 . h1(j-1))
                    __builtin_amdgcn_s_setprio(1);
                    f2 a0, a1; PKDOT2(a0, a1, W2, H1);
                    const float s1 = ((u[k] + a0.x) + a0.y) + (a1.x + a1.y);
                    c[k] = s1;                       // lane10: out(j-1)
                    const float hn = fast_tanh(s1);
                    h1b[lane] = hn;
                    __builtin_amdgcn_s_setprio(0);
                    __builtin_amdgcn_wave_barrier();
                    // ---- filler phase: readback consume ----
                    const float4 q0 = *(const float4*)(h1b);
                    const float4 q1 = *(const float4*)(h1b + 4);
                    const f2     q2 = *(const f2*)(h1b + 8);
                    if (k > 0 || m > 1) {     // mask j = -1 (m=1, k=0)
                        H1[0] = f2{q0.x, q0.y}; H1[1] = f2{q0.z, q0.w};
                        H1[2] = f2{q1.x, q1.y}; H1[3] = f2{q1.z, q1.w};
                        H1[4] = q2;
                    }
                }
                // c[k] = out(32m-34+k); quads with 2-value carry
                if (ol) {
                    if (m == 1) {
                        // out(0..27) = c[2..29]
                        #pragma unroll
                        for (int t = 0; t < 7; ++t)
                            *(float4*)(orow + 4*t) =
                                make_float4(c[4*t+2], c[4*t+3], c[4*t+4], c[4*t+5]);
                    } else {
                        const int tb = 32 * m - 36;
                        *(float4*)(orow + tb) = make_float4(P1, P2, c[0], c[1]);
                        #pragma unroll
                        for (int t = 0; t < 7; ++t)
                            *(float4*)(orow + tb + 4 + 4*t) =
                                make_float4(c[4*t+2], c[4*t+3], c[4*t+4], c[4*t+5]);
                    }
                }
                P1 = c[30]; P2 = c[31];
            }
        }
        __syncthreads();
    }

    // ---- tail: u(2047) publish by A, then B computes h1(2047) + out ----
    if (isA) {
        f2 uc; PKDOT(uc, W1, H0);                // H0 = h0(2047)
        up[63 * 16] = (ub + uc.x) + uc.y;        // slot 2047 & 63 = 63
    }
    __syncthreads();
    if (!isA) {
        const float u47 = up[63 * 16];
        f2 ac; PKDOT(ac, W2, H1);                // H1 = h1(2046)
        const float sA = (u47 + ac.x) + ac.y;    // lane10: out(2046)
        const float h1f = fast_tanh(sA);
        h1b[lane] = h1f;
        __builtin_amdgcn_wave_barrier();
        const float4 q0 = *(const float4*)(h1b);
        const float4 q1 = *(const float4*)(h1b + 4);
        const f2     q2 = *(const f2*)(h1b + 8);
        H1[0] = f2{q0.x, q0.y}; H1[1] = f2{q0.z, q0.w};
        H1[2] = f2{q1.x, q1.y}; H1[3] = f2{q1.z, q1.w};
        H1[4] = q2;                              // h1(2047)
        f2 a2; PKDOT(a2, W2, H1);
        const float o47 = (obias + a2.x) + a2.y; // lane10: out(2047)
        if (ol)
            *(float4*)(orow + TT - 4) = make_float4(P1, P2, sA, o47);
        if (act)
            out[(size_t)BB*TT + (size_t)BB*HID + (size_t)row*HID + lane] = h1f;
    } else {
        if (act)
            out[(size_t)BB*TT + (size_t)row*HID + lane] = hown;   // h0(2047)
    }
}

extern "C" void kernel_launch(void* const* d_in, const int* in_sizes, int n_in,
                              void* d_out, int out_size, void* d_ws, size_t ws_size,
                              hipStream_t stream) {
    const float* x    = (const float*)d_in[0];
    const float* hs   = (const float*)d_in[1];
    const float* Wih0 = (const float*)d_in[2];
    const float* Whh0 = (const float*)d_in[3];
    const float* bih0 = (const float*)d_in[4];
    const float* bhh0 = (const float*)d_in[5];
    const float* Wih1 = (const float*)d_in[6];
    const float* Whh1 = (const float*)d_in[7];
    const float* bih1 = (const float*)d_in[8];
    const float* bhh1 = (const float*)d_in[9];
    const float* Wout = (const float*)d_in[10];
    const float* bout = (const float*)d_in[11];
    float* out = (float*)d_out;

    dim3 grid(BB / 4), block(128);
    hipLaunchKernelGGL(rnn_kernel, grid, block, 0, stream,
        x, hs, Wih0, Whh0, bih0, bhh0, Wih1, Whh1, bih1, bhh1, Wout, bout, out);
}

// Round 25
// 255.285 us; speedup vs baseline: 1.0190x; 1.0190x over previous
//
#include <hip/hip_runtime.h>

#define HID 10
#define TT  2048
#define BB  4096

typedef float f2 __attribute__((ext_vector_type(2)));

static __device__ __forceinline__ f2 pkmul(f2 a, f2 b) {
    f2 d; asm("v_pk_mul_f32 %0, %1, %2" : "=v"(d) : "v"(a), "v"(b)); return d;
}
static __device__ __forceinline__ f2 pkfma(f2 a, f2 b, f2 c) {
    f2 d; asm("v_pk_fma_f32 %0, %1, %2, %3" : "=v"(d) : "v"(a), "v"(b), "v"(c)); return d;
}

__device__ __forceinline__ float fast_tanh(float x) {
    // tanh(x) = 1 - 2/(exp2(x*2*log2e) + 1); saturates correctly at +-inf
    float e = exp2f(x * 2.885390081777926814f);
    float r = __builtin_amdgcn_rcpf(e + 1.0f);
    return fmaf(-2.0f, r, 1.0f);
}

#define PKDOT(ACC, W, H)                 \
    ACC = pkmul(W[0], H[0]);             \
    ACC = pkfma(W[1], H[1], ACC);        \
    ACC = pkfma(W[2], H[2], ACC);        \
    ACC = pkfma(W[3], H[3], ACC);        \
    ACC = pkfma(W[4], H[4], ACC);

// SESSION OPTIMUM (R23, 254us). 2-wave producer-consumer specialization:
//   wave A: h0 recurrence; u(i-1) = Wih1.h0(i-1)+b1 computed on the OLD H0
//           (the u-dot doubles as h0-readback latency cover) and published
//           as ONE f32/lane into a 32-slot ring. Lane10 publishes b_out.
//   wave B: h1 recurrence lag-17; lane10 rides Wout on the Whh1 dot -> its
//           pre-tanh sum = out(j-1); 2-value lag-carry quad stores.
// 16-step epochs (129 barriers); T5 setprio(1) around each chain phase
// (chain-phase waves win issue arbitration vs filler-phase co-residents);
// half-wave bank-phase permute {0,16,8,24} -> zero bank conflicts.
// 2048 waves = 2 waves/SIMD; 344 cyc/step = ~208 issue + ~125 co-stall.
__global__ void __launch_bounds__(128) rnn_kernel(
    const float* __restrict__ x,    const float* __restrict__ hs,
    const float* __restrict__ Wih0, const float* __restrict__ Whh0,
    const float* __restrict__ bih0, const float* __restrict__ bhh0,
    const float* __restrict__ Wih1, const float* __restrict__ Whh1,
    const float* __restrict__ bih1, const float* __restrict__ bhh1,
    const float* __restrict__ Wout, const float* __restrict__ boutp,
    float* __restrict__ out)
{
    const int tid  = threadIdx.x;
    const bool isA = tid < 64;
    const int lane = tid & 15;           // hidden unit slot
    const int grp  = (tid >> 4) & 3;     // row within block
    const int row  = blockIdx.x * 4 + grp;
    const bool act = (lane < HID);
    const bool ol  = (lane == HID);      // rider lane

    // stride 552 (mod 32 = 8); permuted bases {0,2,1,3} -> half-wave bank
    // phases {0,16}/{8,24}. Regions per group: u-ring [32][16] f32 @0,
    // h0 buf @512, h1 buf @528.
    __shared__ float lds[4 * 552];
    const int pg = ((grp << 1) | (grp >> 1)) & 3;   // {0,2,1,3}
    float* base = &lds[pg * 552];
    float* up   = base + lane;           // u-ring lane pointer
    float* h0b  = base + 512;
    float* h1b  = base + 528;

    const float* xrow = x   + (size_t)row * TT;
    float*       orow = out + (size_t)row * TT;

    // ---- role state ----
    f2 W0[5], W1[5], W2[5], H0[5], H1[5];
    float wih0i = 0.f, b0c = 0.f, ub = 0.f, obias = 0.f;
    float hown = 0.f;
    float4 xa, xb, xc, xd;
    float P1 = 0.f, P2 = 0.f;

    if (isA) {
        #pragma unroll
        for (int j = 0; j < 5; ++j) {
            W0[j] = act ? f2{Whh0[lane*HID + 2*j], Whh0[lane*HID + 2*j+1]}
                        : f2{0.f, 0.f};
            W1[j] = act ? f2{Wih1[lane*HID + 2*j], Wih1[lane*HID + 2*j+1]}
                        : f2{0.f, 0.f};
            H0[j] = f2{hs[row*HID + 2*j], hs[row*HID + 2*j+1]};
        }
        wih0i = act ? Wih0[lane] : 0.f;
        b0c   = act ? (bih0[lane] + bhh0[lane]) : 0.f;
        ub    = act ? (bih1[lane] + bhh1[lane]) : (ol ? boutp[0] : 0.f);
        hown  = act ? hs[row*HID + lane] : 0.f;
        xa = *(const float4*)(xrow);
        xb = *(const float4*)(xrow + 4);
        xc = *(const float4*)(xrow + 8);
        xd = *(const float4*)(xrow + 12);
    } else {
        #pragma unroll
        for (int j = 0; j < 5; ++j) {
            W2[j] = act ? f2{Whh1[lane*HID + 2*j], Whh1[lane*HID + 2*j+1]}
                  : (ol ? f2{Wout[2*j], Wout[2*j+1]} : f2{0.f, 0.f});
            H1[j] = f2{hs[BB*HID + row*HID + 2*j], hs[BB*HID + row*HID + 2*j+1]};
        }
        obias = ol ? boutp[0] : 0.f;
    }

    // A epochs 0..127 (steps i=16m..16m+15, publishes u(16m-1..16m+14));
    // B epochs 1..128 (j = 16(m-1)-1..16(m-1)+14, lag-17 behind A's window).
    for (int m = 0; m <= 128; ++m) {
        if (isA) {
            if (m <= 127) {
                const int mn = (m + 1 <= 127) ? m + 1 : 127;
                const float4 n0 = *(const float4*)(xrow + 16 * mn);
                const float4 n1 = *(const float4*)(xrow + 16 * mn + 4);
                const float4 n2 = *(const float4*)(xrow + 16 * mn + 8);
                const float4 n3 = *(const float4*)(xrow + 16 * mn + 12);
                const float xs[16] = {xa.x, xa.y, xa.z, xa.w,
                                      xb.x, xb.y, xb.z, xb.w,
                                      xc.x, xc.y, xc.z, xc.w,
                                      xd.x, xd.y, xd.z, xd.w};
                const int sb = (m & 1) * 16;
                #pragma unroll
                for (int k = 0; k < 16; ++k) {
                    // ---- chain phase: prio 1 ----
                    __builtin_amdgcn_s_setprio(1);
                    f2 ac; PKDOT(ac, W0, H0);
                    const float s0 = fmaf(xs[k], wih0i, b0c);
                    hown = fast_tanh((s0 + ac.x) + ac.y);
                    h0b[lane] = hown;
                    __builtin_amdgcn_s_setprio(0);
                    __builtin_amdgcn_wave_barrier();
                    // ---- filler phase: readback + u-dot on OLD H0 ----
                    const float4 r0 = *(const float4*)(h0b);
                    const float4 r1 = *(const float4*)(h0b + 4);
                    const f2     r2 = *(const f2*)(h0b + 8);
                    f2 uc; PKDOT(uc, W1, H0);
                    up[((sb + k + 31) & 31) * 16] = (ub + uc.x) + uc.y;
                    H0[0] = f2{r0.x, r0.y}; H0[1] = f2{r0.z, r0.w};
                    H0[2] = f2{r1.x, r1.y}; H0[3] = f2{r1.z, r1.w};
                    H0[4] = r2;
                }
                xa = n0; xb = n1; xc = n2; xd = n3;
            }
        } else {
            if (m >= 1) {
                const int sbB = ((m - 1) & 1) * 16;
                float u[16];
                #pragma unroll
                for (int k = 0; k < 16; ++k)
                    u[k] = up[((sbB + k + 31) & 31) * 16];
                float c[16];
                #pragma unroll
                for (int k = 0; k < 16; ++k) {
                    // j = 16(m-1)-1+k; h1(j) = tanh(u(j) + Whh1 . h1(j-1))
                    __builtin_amdgcn_s_setprio(1);
                    f2 ac; PKDOT(ac, W2, H1);
                    const float s1 = (u[k] + ac.x) + ac.y;  // lane10: out(j-1)
                    c[k] = s1;
                    const float hn = fast_tanh(s1);
                    h1b[lane] = hn;
                    __builtin_amdgcn_s_setprio(0);
                    __builtin_amdgcn_wave_barrier();
                    // ---- filler phase: readback consume ----
                    const float4 q0 = *(const float4*)(h1b);
                    const float4 q1 = *(const float4*)(h1b + 4);
                    const f2     q2 = *(const f2*)(h1b + 8);
                    if (k > 0 || m > 1) {     // mask j = -1 (m=1, k=0)
                        H1[0] = f2{q0.x, q0.y}; H1[1] = f2{q0.z, q0.w};
                        H1[2] = f2{q1.x, q1.y}; H1[3] = f2{q1.z, q1.w};
                        H1[4] = q2;
                    }
                }
                // c[k] = out(16m-18+k); quads with 2-value carry
                if (ol) {
                    if (m == 1) {
                        *(float4*)(orow)     = make_float4(c[2],  c[3],  c[4],  c[5]);
                        *(float4*)(orow + 4) = make_float4(c[6],  c[7],  c[8],  c[9]);
                        *(float4*)(orow + 8) = make_float4(c[10], c[11], c[12], c[13]);
                    } else {
                        const int tb = 16 * m - 20;
                        *(float4*)(orow + tb)      = make_float4(P1,    P2,    c[0],  c[1]);
                        *(float4*)(orow + tb + 4)  = make_float4(c[2],  c[3],  c[4],  c[5]);
                        *(float4*)(orow + tb + 8)  = make_float4(c[6],  c[7],  c[8],  c[9]);
                        *(float4*)(orow + tb + 12) = make_float4(c[10], c[11], c[12], c[13]);
                    }
                }
                P1 = c[14]; P2 = c[15];
            }
        }
        __syncthreads();
    }

    // ---- tail: u(2047) publish by A, then B computes h1(2047) + out ----
    if (isA) {
        f2 uc; PKDOT(uc, W1, H0);                // H0 = h0(2047)
        up[31 * 16] = (ub + uc.x) + uc.y;        // slot 2047 & 31 = 31
    }
    __syncthreads();
    if (!isA) {
        const float u47 = up[31 * 16];
        f2 ac; PKDOT(ac, W2, H1);                // H1 = h1(2046)
        const float sA = (u47 + ac.x) + ac.y;    // lane10: out(2046)
        const float h1f = fast_tanh(sA);
        h1b[lane] = h1f;
        __builtin_amdgcn_wave_barrier();
        const float4 q0 = *(const float4*)(h1b);
        const float4 q1 = *(const float4*)(h1b + 4);
        const f2     q2 = *(const f2*)(h1b + 8);
        H1[0] = f2{q0.x, q0.y}; H1[1] = f2{q0.z, q0.w};
        H1[2] = f2{q1.x, q1.y}; H1[3] = f2{q1.z, q1.w};
        H1[4] = q2;                              // h1(2047)
        f2 a2; PKDOT(a2, W2, H1);
        const float o47 = (obias + a2.x) + a2.y; // lane10: out(2047)
        if (ol)
            *(float4*)(orow + TT - 4) = make_float4(P1, P2, sA, o47);
        if (act)
            out[(size_t)BB*TT + (size_t)BB*HID + (size_t)row*HID + lane] = h1f;
    } else {
        if (act)
            out[(size_t)BB*TT + (size_t)row*HID + lane] = hown;   // h0(2047)
    }
}

extern "C" void kernel_launch(void* const* d_in, const int* in_sizes, int n_in,
                              void* d_out, int out_size, void* d_ws, size_t ws_size,
                              hipStream_t stream) {
    const float* x    = (const float*)d_in[0];
    const float* hs   = (const float*)d_in[1];
    const float* Wih0 = (const float*)d_in[2];
    const float* Whh0 = (const float*)d_in[3];
    const float* bih0 = (const float*)d_in[4];
    const float* bhh0 = (const float*)d_in[5];
    const float* Wih1 = (const float*)d_in[6];
    const float* Whh1 = (const float*)d_in[7];
    const float* bih1 = (const float*)d_in[8];
    const float* bhh1 = (const float*)d_in[9];
    const float* Wout = (const float*)d_in[10];
    const float* bout = (const float*)d_in[11];
    float* out = (float*)d_out;

    dim3 grid(BB / 4), block(128);
    hipLaunchKernelGGL(rnn_kernel, grid, block, 0, stream,
        x, hs, Wih0, Whh0, bih0, bhh0, Wih1, Whh1, bih1, bhh1, Wout, bout, out);
}